// Round 1
// baseline (1386.685 us; speedup 1.0000x reference)
//
#include <hip/hip_runtime.h>
#include <hip/hip_bf16.h>

typedef float f32x4 __attribute__((ext_vector_type(4)));
typedef short s16x8 __attribute__((ext_vector_type(8)));

#define N_NODES 50176

static __device__ __forceinline__ ushort f2bf(float x) {
    __hip_bfloat16 h = __float2bfloat16(x);
    return *reinterpret_cast<ushort*>(&h);
}
static __device__ __forceinline__ float bf2f(ushort u) {
    __hip_bfloat16 h = *reinterpret_cast<__hip_bfloat16*>(&u);
    return __bfloat162float(h);
}

// ---------------- weight prep: transpose+cast to bf16 [n][k], zero accumulators ----------------
__global__ void k_prep(const float* W1r, const float* W1t, const float* W2r, const float* W2t,
                       const float* decW, ushort* Bt1, ushort* Bt2, ushort* Bt3, float* decLast,
                       float* alpha_sum, float* bn_acc) {
    int idx = blockIdx.x * 256 + threadIdx.x;
    if (idx < 1024 * 1024) {               // Bt1[j][k] = [W1rel | W1root](k, j)
        int j = idx >> 10, k = idx & 1023;
        float v = (j < 512) ? W1r[k * 512 + j] : W1t[k * 512 + (j - 512)];
        Bt1[idx] = f2bf(v);
    }
    if (idx < 1024 * 512) {                // Bt2[j][k], K=512
        int j = idx >> 9, k = idx & 511;
        float v = (j < 512) ? W2r[k * 512 + j] : W2t[k * 512 + (j - 512)];
        Bt2[idx] = f2bf(v);
    }
    if (idx < 512 * 512) {                 // Bt3[j][k] = decW(k, j), first 512 rows
        int j = idx >> 9, k = idx & 511;
        Bt3[idx] = f2bf(decW[k * 512 + j]);
    }
    if (idx < 512) decLast[idx] = decW[512 * 512 + idx];  // decW row 512 (node_w column)
    if (idx < 2048) bn_acc[idx] = 0.f;
    if (idx == 0) alpha_sum[0] = 0.f;
}

// ---------------- NCHW (vis|tac) -> node_bf16 [N][1024], LDS-tiled transpose ----------------
__global__ void k_transpose(const float* vis, const float* tac, ushort* nodeb) {
    int b = blockIdx.x, tid = threadIdx.x;
    __shared__ ushort tile[128 * 50];
    for (int chunk = 0; chunk < 8; ++chunk) {
        const float* src = (chunk < 4 ? vis : tac) + ((size_t)b * 512 + (chunk & 3) * 128) * 49;
        for (int p = tid; p < 128 * 49; p += 256) {
            int d = p / 49, n = p - d * 49;
            tile[d * 50 + n] = f2bf(src[p]);       // coalesced read: n fastest
        }
        __syncthreads();
        for (int p = tid; p < 49 * 128; p += 256) {
            int n = p >> 7, d = p & 127;
            nodeb[((size_t)(b * 49 + n)) * 1024 + chunk * 128 + d] = tile[d * 50 + n]; // coalesced write: d fastest
        }
        __syncthreads();
    }
}

// ---------------- coords = node @ proj_W + proj_b ; one wave per node ----------------
__global__ void k_coords(const ushort* nodeb, const float* projW, const float* projb, float* coords) {
    __shared__ float pw[2048];
    int tid = threadIdx.x;
    for (int p = tid; p < 2048; p += 256) pw[p] = projW[p];
    __syncthreads();
    int lane = tid & 63, wave = tid >> 6;
    int n = blockIdx.x * 4 + wave;
    const ushort* row = nodeb + (size_t)n * 1024;
    float c0 = 0.f, c1 = 0.f;
    for (int j = 0; j < 16; ++j) {
        int d = j * 64 + lane;
        float v = bf2f(row[d]);
        c0 += v * pw[2 * d];
        c1 += v * pw[2 * d + 1];
    }
    for (int off = 32; off; off >>= 1) { c0 += __shfl_down(c0, off); c1 += __shfl_down(c1, off); }
    if (lane == 0) { coords[2 * n] = c0 + projb[0]; coords[2 * n + 1] = c1 + projb[1]; }
}

// ---------------- per-graph edges: edge_attr, exp(edge_attr), global alpha sum, node_w ----------------
// edge order (ours): horizontal h(r,c)=r*6+c for (r,c)-(r,c+1); vertical v(r,c)=42+r*7+c for (r,c)-(r+1,c)
__global__ void k_edges(const float* coords, float* ew_exp, float* node_w, float* alpha_sum) {
    int b = blockIdx.x, tid = threadIdx.x;  // blockDim = 128
    __shared__ float cx[49], cy[49], ea[84];
    __shared__ float wsum[2];
    if (tid < 49) { cx[tid] = coords[(b * 49 + tid) * 2]; cy[tid] = coords[(b * 49 + tid) * 2 + 1]; }
    __syncthreads();
    float ex = 0.f;
    if (tid < 84) {
        int s, d2;
        if (tid < 42) { int r = tid / 6, c = tid - r * 6; s = r * 7 + c; d2 = s + 1; }
        else { int t = tid - 42; int r = t / 7, c = t - r * 7; s = r * 7 + c; d2 = s + 7; }
        float dx = cx[s] - cx[d2], dy = cy[s] - cy[d2];
        float dist = sqrtf(dx * dx + dy * dy);
        float attr = 1.f / (1.f + expf(-(1.f / (dist + 1e-6f))));
        ea[tid] = attr;
        ex = expf(attr);
        ew_exp[b * 84 + tid] = ex;
    }
    for (int off = 32; off; off >>= 1) ex += __shfl_down(ex, off);
    if ((tid & 63) == 0) wsum[tid >> 6] = ex;
    __syncthreads();
    if (tid == 0) atomicAdd(alpha_sum, wsum[0] + wsum[1]);
    if (tid < 49) {
        int r = tid / 7, c = tid - r * 7;
        float s = 0.f; int cnt = 0;
        if (c > 0) { s += ea[r * 6 + c - 1]; cnt++; }
        if (c < 6) { s += ea[r * 6 + c]; cnt++; }
        if (r > 0) { s += ea[42 + (r - 1) * 7 + c]; cnt++; }
        if (r < 6) { s += ea[42 + r * 7 + c]; cnt++; }
        node_w[b * 49 + tid] = s / (float)cnt;
    }
}

// ---------------- bf16 MFMA GEMM: C[M][Nc] = A[M][K] @ Bt[Nc][K]^T ----------------
// 128x128 tile, BK=32, 4 waves each 64x64 (4x4 of 16x16x32), padded LDS rows (40 elems)
template <int EPI>
__global__ __launch_bounds__(256, 2)
void k_gemm(const ushort* __restrict__ A, const ushort* __restrict__ Bt, float* __restrict__ C,
            int Nc, int K,
            const float* __restrict__ node_w, const float* __restrict__ decLast,
            const float* __restrict__ decb, float* __restrict__ out) {
    __shared__ ushort As[128 * 40];
    __shared__ ushort Bs[128 * 40];
    const int ntiles = Nc >> 7;
    const int rowb = blockIdx.x / ntiles, colb = blockIdx.x % ntiles;
    const int row0 = rowb << 7, col0 = colb << 7;
    const int tid = threadIdx.x;
    const int lane = tid & 63, wave = tid >> 6;
    const int wm = (wave & 1) << 6, wn = (wave >> 1) << 6;
    const int quad = lane >> 4, l16 = lane & 15;
    const int K8 = K >> 3;

    const uint4* Ag = (const uint4*)A;
    const uint4* Bg = (const uint4*)Bt;
    uint4* As4 = (uint4*)As;
    uint4* Bs4 = (uint4*)Bs;

    const int r0s = tid >> 2, kc = tid & 3;                  // chunk: 16B of 8 consecutive k
    const size_t ia0 = (size_t)(row0 + r0s) * K8 + kc;
    const size_t ia1 = (size_t)(row0 + r0s + 64) * K8 + kc;
    const size_t ib0 = (size_t)(col0 + r0s) * K8 + kc;
    const size_t ib1 = (size_t)(col0 + r0s + 64) * K8 + kc;
    const int sa0 = r0s * 5 + kc, sa1 = (r0s + 64) * 5 + kc; // uint4 index, row stride 5 (=40 ushorts)

    f32x4 acc[4][4];
#pragma unroll
    for (int i = 0; i < 4; ++i)
#pragma unroll
        for (int j = 0; j < 4; ++j) acc[i][j] = (f32x4)0.f;

    const int nk = K >> 5;
    uint4 a0 = Ag[ia0], a1 = Ag[ia1], b0 = Bg[ib0], b1 = Bg[ib1];
    for (int kt = 0; kt < nk; ++kt) {
        As4[sa0] = a0; As4[sa1] = a1; Bs4[sa0] = b0; Bs4[sa1] = b1;
        __syncthreads();
        if (kt + 1 < nk) {
            const size_t o = (size_t)(kt + 1) * 4;
            a0 = Ag[ia0 + o]; a1 = Ag[ia1 + o]; b0 = Bg[ib0 + o]; b1 = Bg[ib1 + o];
        }
        s16x8 af[4], bf[4];
#pragma unroll
        for (int i = 0; i < 4; ++i) af[i] = *(const s16x8*)&As[(wm + i * 16 + l16) * 40 + quad * 8];
#pragma unroll
        for (int j = 0; j < 4; ++j) bf[j] = *(const s16x8*)&Bs[(wn + j * 16 + l16) * 40 + quad * 8];
#pragma unroll
        for (int i = 0; i < 4; ++i)
#pragma unroll
            for (int j = 0; j < 4; ++j)
                acc[i][j] = __builtin_amdgcn_mfma_f32_16x16x32_bf16(af[i], bf[j], acc[i][j], 0, 0, 0);
        __syncthreads();
    }
#pragma unroll
    for (int i = 0; i < 4; ++i) {
#pragma unroll
        for (int j = 0; j < 4; ++j) {
#pragma unroll
            for (int r = 0; r < 4; ++r) {
                int m = row0 + wm + i * 16 + quad * 4 + r;
                int n = col0 + wn + j * 16 + l16;
                float v = acc[i][j][r];
                if (EPI == 0) {
                    C[(size_t)m * Nc + n] = v;
                } else {
                    v += node_w[m] * decLast[n] + decb[n];
                    v = fmaxf(v, 0.f);
                    int bb = m / 49, sp = m - bb * 49;
                    out[((size_t)bb * 512 + n) * 49 + sp] = v;   // (B,512,7,7)
                }
            }
        }
    }
}

// ---------------- aggregation: x = alpha-weighted in-neighbor avg of H + R + bias; BN partial sums ----------------
__global__ void k_agg(const float* __restrict__ P, const float* __restrict__ ew_exp,
                      const float* __restrict__ alpha_sum, const float* __restrict__ bias,
                      float* __restrict__ xout, float* __restrict__ bn_sum, float* __restrict__ bn_sumsq) {
    int T = blockIdx.x * 256 + threadIdx.x;   // grid 256 blocks: 512 d-cols x 128 row-walkers
    int d = T & 511, p = T >> 9;
    float inv_s = 1.f / (alpha_sum[0] + 1e-8f);
    float s = 0.f, s2 = 0.f;
    float bd = bias[d];
    for (int n = p; n < N_NODES; n += 128) {
        int b = n / 49, sp = n - b * 49;
        int r = sp / 7, c = sp - r * 7;
        float v = P[(size_t)n * 1024 + 512 + d] + bd;       // root + bias
        float agg = 0.f; int deg = 0;
        if (c > 0) { agg += ew_exp[b * 84 + r * 6 + (c - 1)] * P[(size_t)(n - 1) * 1024 + d]; deg++; }
        if (r > 0) { agg += ew_exp[b * 84 + 42 + (r - 1) * 7 + c] * P[(size_t)(n - 7) * 1024 + d]; deg++; }
        if (deg) v += agg * inv_s / (float)deg;
        xout[(size_t)n * 512 + d] = v;
        s += v; s2 += v * v;
    }
    atomicAdd(&bn_sum[d], s);
    atomicAdd(&bn_sumsq[d], s2);
}

// ---------------- BN scale/shift from sums ----------------
__global__ void k_bnstat(const float* bn_sum, const float* bn_sumsq, const float* gamma, const float* beta,
                         float* scale, float* shift) {
    int d = threadIdx.x;
    const float invN = 1.f / (float)N_NODES;
    float mu = bn_sum[d] * invN;
    float var = bn_sumsq[d] * invN - mu * mu;
    float sc = gamma[d] * rsqrtf(var + 1e-5f);
    scale[d] = sc;
    shift[d] = beta[d] - mu * sc;
}

// ---------------- BN apply + relu + bf16 cast ----------------
__global__ void k_bnapply(const float* __restrict__ x, const float* __restrict__ scale,
                          const float* __restrict__ shift, ushort* __restrict__ xb) {
    __shared__ float ls[512], lh[512];
    int tid = threadIdx.x;
    for (int p = tid; p < 512; p += 256) { ls[p] = scale[p]; lh[p] = shift[p]; }
    __syncthreads();
    size_t i = (size_t)blockIdx.x * 256 + tid;
    float4 v = ((const float4*)x)[i];
    int d0 = (int)((i * 4) & 511);
    ushort4 o;
    o.x = f2bf(fmaxf(v.x * ls[d0] + lh[d0], 0.f));
    o.y = f2bf(fmaxf(v.y * ls[d0 + 1] + lh[d0 + 1], 0.f));
    o.z = f2bf(fmaxf(v.z * ls[d0 + 2] + lh[d0 + 2], 0.f));
    o.w = f2bf(fmaxf(v.w * ls[d0 + 3] + lh[d0 + 3], 0.f));
    ((ushort4*)xb)[i] = o;
}

extern "C" void kernel_launch(void* const* d_in, const int* in_sizes, int n_in,
                              void* d_out, int out_size, void* d_ws, size_t ws_size,
                              hipStream_t stream) {
    const float* vis   = (const float*)d_in[0];
    const float* tac   = (const float*)d_in[1];
    const float* projW = (const float*)d_in[2];
    const float* projb = (const float*)d_in[3];
    const float* W1r   = (const float*)d_in[4];
    const float* b1    = (const float*)d_in[5];
    const float* W1t   = (const float*)d_in[6];
    const float* g1    = (const float*)d_in[7];
    const float* be1   = (const float*)d_in[8];
    const float* W2r   = (const float*)d_in[9];
    const float* b2    = (const float*)d_in[10];
    const float* W2t   = (const float*)d_in[11];
    const float* g2    = (const float*)d_in[12];
    const float* be2   = (const float*)d_in[13];
    const float* decW  = (const float*)d_in[14];
    const float* decb  = (const float*)d_in[15];
    float* out = (float*)d_out;

    char* p = (char*)d_ws;
    ushort* nodeb = (ushort*)p; p += 102760448;          // [N][1024] bf16
    float*  P     = (float*)p;  p += 205520896;          // [N][1024] f32 (GEMM1/GEMM2 out)
    ushort* xb    = (ushort*)p; p += 51380224;           // [N][512] bf16 activations
    float* coords = (float*)p;  p += 401408;             // [N][2]
    float* ew     = (float*)p;  p += 344064;             // [1024][84] exp(edge_attr)
    float* nw     = (float*)p;  p += 200704;             // [N] node_w
    ushort* Bt1   = (ushort*)p; p += 2097152;            // [1024][1024] bf16
    ushort* Bt2   = (ushort*)p; p += 1048576;            // [1024][512]
    ushort* Bt3   = (ushort*)p; p += 524288;             // [512][512]
    float* decLast = (float*)p; p += 2048;               // [512]
    float* asum   = (float*)p;  p += 256;                // scalar
    float* bnacc  = (float*)p;  p += 4 * 512 * 4;        // sum1,sq1,sum2,sq2
    float* scsh   = (float*)p;  p += 4 * 512 * 4;        // scale1,shift1,scale2,shift2
    float* bn1s = bnacc, *bn1q = bnacc + 512, *bn2s = bnacc + 1024, *bn2q = bnacc + 1536;
    float* sc1 = scsh, *sh1 = scsh + 512, *sc2 = scsh + 1024, *sh2 = scsh + 1536;

    float* xpre = out;  // d_out doubles as f32 [N][512] scratch; final GEMM overwrites it fully

    k_prep<<<4096, 256, 0, stream>>>(W1r, W1t, W2r, W2t, decW, Bt1, Bt2, Bt3, decLast, asum, bnacc);
    k_transpose<<<1024, 256, 0, stream>>>(vis, tac, nodeb);
    k_coords<<<12544, 256, 0, stream>>>(nodeb, projW, projb, coords);
    k_edges<<<1024, 128, 0, stream>>>(coords, ew, nw, asum);

    k_gemm<0><<<392 * 8, 256, 0, stream>>>(nodeb, Bt1, P, 1024, 1024, nullptr, nullptr, nullptr, nullptr);
    k_agg<<<256, 256, 0, stream>>>(P, ew, asum, b1, xpre, bn1s, bn1q);
    k_bnstat<<<1, 512, 0, stream>>>(bn1s, bn1q, g1, be1, sc1, sh1);
    k_bnapply<<<25088, 256, 0, stream>>>(xpre, sc1, sh1, xb);

    k_gemm<0><<<392 * 8, 256, 0, stream>>>(xb, Bt2, P, 1024, 512, nullptr, nullptr, nullptr, nullptr);
    k_agg<<<256, 256, 0, stream>>>(P, ew, asum, b2, xpre, bn2s, bn2q);
    k_bnstat<<<1, 512, 0, stream>>>(bn2s, bn2q, g2, be2, sc2, sh2);
    k_bnapply<<<25088, 256, 0, stream>>>(xpre, sc2, sh2, xb);

    k_gemm<1><<<392 * 4, 256, 0, stream>>>(xb, Bt3, nullptr, 512, 512, nw, decLast, decb, out);
}

// Round 2
// 816.863 us; speedup vs baseline: 1.6976x; 1.6976x over previous
//
#include <hip/hip_runtime.h>
#include <hip/hip_bf16.h>

typedef float f32x4 __attribute__((ext_vector_type(4)));
typedef short s16x8 __attribute__((ext_vector_type(8)));

#define N_NODES 50176

static __device__ __forceinline__ ushort f2bf(float x) {
    __hip_bfloat16 h = __float2bfloat16(x);
    return *reinterpret_cast<ushort*>(&h);
}
static __device__ __forceinline__ float bf2f(ushort u) {
    __hip_bfloat16 h = *reinterpret_cast<__hip_bfloat16*>(&u);
    return __bfloat162float(h);
}

// ---------------- weight prep: Bt1[512][2048]=[W1rel;W1root]^T, Bt2[512][1024], Bt3[512][512]; zero accum ----------------
__global__ void k_prep(const float* W1r, const float* W1t, const float* W2r, const float* W2t,
                       const float* decW, ushort* Bt1, ushort* Bt2, ushort* Bt3, float* decLast,
                       float* alpha_sum, float* bn_acc) {
    int idx = blockIdx.x * 256 + threadIdx.x;
    if (idx < 512 * 2048) {                // Bt1[j][k]: k<1024 -> W1rel[k][j], else W1root[k-1024][j]
        int j = idx >> 11, k = idx & 2047;
        float v = (k < 1024) ? W1r[k * 512 + j] : W1t[(k - 1024) * 512 + j];
        Bt1[idx] = f2bf(v);
    }
    if (idx < 512 * 1024) {                // Bt2[j][k]: k<512 -> W2rel[k][j], else W2root[k-512][j]
        int j = idx >> 10, k = idx & 1023;
        float v = (k < 512) ? W2r[k * 512 + j] : W2t[(k - 512) * 512 + j];
        Bt2[idx] = f2bf(v);
    }
    if (idx < 512 * 512) {                 // Bt3[j][k] = decW(k, j)
        int j = idx >> 9, k = idx & 511;
        Bt3[idx] = f2bf(decW[k * 512 + j]);
    }
    if (idx < 512) decLast[idx] = decW[512 * 512 + idx];
    if (idx < 2048) bn_acc[idx] = 0.f;
    if (idx == 0) alpha_sum[0] = 0.f;
}

// ---------------- NCHW (vis|tac) -> xcat1 cols [1024..2048) bf16, LDS-tiled transpose ----------------
__global__ void k_transpose(const float* vis, const float* tac, ushort* xcat1) {
    int b = blockIdx.x, tid = threadIdx.x;
    __shared__ ushort tile[128 * 50];
    for (int chunk = 0; chunk < 8; ++chunk) {
        const float* src = (chunk < 4 ? vis : tac) + ((size_t)b * 512 + (chunk & 3) * 128) * 49;
        for (int p = tid; p < 128 * 49; p += 256) {
            int d = p / 49, n = p - d * 49;
            tile[d * 50 + n] = f2bf(src[p]);
        }
        __syncthreads();
        for (int p = tid; p < 49 * 128; p += 256) {
            int n = p >> 7, d = p & 127;
            xcat1[((size_t)(b * 49 + n)) * 2048 + 1024 + chunk * 128 + d] = tile[d * 50 + n];
        }
        __syncthreads();
    }
}

// ---------------- coords = node @ proj_W + proj_b ; one wave per node ----------------
__global__ void k_coords(const ushort* xcat1, const float* projW, const float* projb, float* coords) {
    __shared__ float pw[2048];
    int tid = threadIdx.x;
    for (int p = tid; p < 2048; p += 256) pw[p] = projW[p];
    __syncthreads();
    int lane = tid & 63, wave = tid >> 6;
    int n = blockIdx.x * 4 + wave;
    const ushort* row = xcat1 + (size_t)n * 2048 + 1024;
    float c0 = 0.f, c1 = 0.f;
    for (int j = 0; j < 16; ++j) {
        int d = j * 64 + lane;
        float v = bf2f(row[d]);
        c0 += v * pw[2 * d];
        c1 += v * pw[2 * d + 1];
    }
    for (int off = 32; off; off >>= 1) { c0 += __shfl_down(c0, off); c1 += __shfl_down(c1, off); }
    if (lane == 0) { coords[2 * n] = c0 + projb[0]; coords[2 * n + 1] = c1 + projb[1]; }
}

// ---------------- per-graph edges: exp(edge_attr), global alpha sum, node_w ----------------
__global__ void k_edges(const float* coords, float* ew_exp, float* node_w, float* alpha_sum) {
    int b = blockIdx.x, tid = threadIdx.x;  // blockDim = 128
    __shared__ float cx[49], cy[49], ea[84];
    __shared__ float wsum[2];
    if (tid < 49) { cx[tid] = coords[(b * 49 + tid) * 2]; cy[tid] = coords[(b * 49 + tid) * 2 + 1]; }
    __syncthreads();
    float ex = 0.f;
    if (tid < 84) {
        int s, d2;
        if (tid < 42) { int r = tid / 6, c = tid - r * 6; s = r * 7 + c; d2 = s + 1; }
        else { int t = tid - 42; int r = t / 7, c = t - r * 7; s = r * 7 + c; d2 = s + 7; }
        float dx = cx[s] - cx[d2], dy = cy[s] - cy[d2];
        float dist = sqrtf(dx * dx + dy * dy);
        float attr = 1.f / (1.f + expf(-(1.f / (dist + 1e-6f))));
        ea[tid] = attr;
        ex = expf(attr);
        ew_exp[b * 84 + tid] = ex;
    }
    for (int off = 32; off; off >>= 1) ex += __shfl_down(ex, off);
    if ((tid & 63) == 0) wsum[tid >> 6] = ex;
    __syncthreads();
    if (tid == 0) atomicAdd(alpha_sum, wsum[0] + wsum[1]);
    if (tid < 49) {
        int r = tid / 7, c = tid - r * 7;
        float s = 0.f; int cnt = 0;
        if (c > 0) { s += ea[r * 6 + c - 1]; cnt++; }
        if (c < 6) { s += ea[r * 6 + c]; cnt++; }
        if (r > 0) { s += ea[42 + (r - 1) * 7 + c]; cnt++; }
        if (r < 6) { s += ea[42 + r * 7 + c]; cnt++; }
        node_w[b * 49 + tid] = s / (float)cnt;
    }
}

// ---------------- input-side aggregation: xcat1 cols [0..1024) = weighted in-neighbor avg of node ----------------
__global__ void k_aggin(ushort* __restrict__ xcat, const float* __restrict__ ew,
                        const float* __restrict__ asum) {
    int T = blockIdx.x * 256 + threadIdx.x;    // N * 128 chunks of 8 bf16
    int n = T >> 7, ch = T & 7 * 16 + 15;      // (T & 127)
    ch = T & 127;
    int b = n / 49, sp = n - b * 49;
    int r = sp / 7, c = sp - r * 7;
    float acc[8];
#pragma unroll
    for (int k = 0; k < 8; ++k) acc[k] = 0.f;
    int deg = (c > 0) + (r > 0);
    if (deg) {
        float sc = (1.f / (asum[0] + 1e-8f)) / (float)deg;
        if (c > 0) {
            float wl = ew[b * 84 + r * 6 + (c - 1)] * sc;
            s16x8 lv = *(const s16x8*)(xcat + (size_t)(n - 1) * 2048 + 1024 + ch * 8);
#pragma unroll
            for (int k = 0; k < 8; ++k) acc[k] += wl * bf2f((ushort)lv[k]);
        }
        if (r > 0) {
            float wt = ew[b * 84 + 42 + (r - 1) * 7 + c] * sc;
            s16x8 tv = *(const s16x8*)(xcat + (size_t)(n - 7) * 2048 + 1024 + ch * 8);
#pragma unroll
            for (int k = 0; k < 8; ++k) acc[k] += wt * bf2f((ushort)tv[k]);
        }
    }
    s16x8 o;
#pragma unroll
    for (int k = 0; k < 8; ++k) o[k] = (short)f2bf(acc[k]);
    *(s16x8*)(xcat + (size_t)n * 2048 + ch * 8) = o;
}

// ---------------- bf16 MFMA GEMM: C[M][512] = A[M][K] @ Bt[512][K]^T (+bias, +BN stats | dec epilogue) ----------------
template <int EPI>
__global__ __launch_bounds__(256, 2)
void k_gemm(const ushort* __restrict__ A, const ushort* __restrict__ Bt, float* __restrict__ C,
            int K,
            const float* __restrict__ bias, float* __restrict__ bn_sum, float* __restrict__ bn_sumsq,
            const float* __restrict__ node_w, const float* __restrict__ decLast,
            const float* __restrict__ decb, float* __restrict__ out) {
    __shared__ ushort As[128 * 40];
    __shared__ ushort Bs[128 * 40];
    const int rowb = blockIdx.x >> 2, colb = blockIdx.x & 3;
    const int row0 = rowb << 7, col0 = colb << 7;
    const int tid = threadIdx.x;
    const int lane = tid & 63, wave = tid >> 6;
    const int wm = (wave & 1) << 6, wn = (wave >> 1) << 6;
    const int quad = lane >> 4, l16 = lane & 15;
    const int K8 = K >> 3;

    const uint4* Ag = (const uint4*)A;
    const uint4* Bg = (const uint4*)Bt;
    uint4* As4 = (uint4*)As;
    uint4* Bs4 = (uint4*)Bs;

    const int r0s = tid >> 2, kc = tid & 3;
    const size_t ia0 = (size_t)(row0 + r0s) * K8 + kc;
    const size_t ia1 = (size_t)(row0 + r0s + 64) * K8 + kc;
    const size_t ib0 = (size_t)(col0 + r0s) * K8 + kc;
    const size_t ib1 = (size_t)(col0 + r0s + 64) * K8 + kc;
    const int sa0 = r0s * 5 + kc, sa1 = (r0s + 64) * 5 + kc;

    f32x4 acc[4][4];
#pragma unroll
    for (int i = 0; i < 4; ++i)
#pragma unroll
        for (int j = 0; j < 4; ++j) acc[i][j] = (f32x4)0.f;

    const int nk = K >> 5;
    uint4 a0 = Ag[ia0], a1 = Ag[ia1], b0 = Bg[ib0], b1 = Bg[ib1];
    for (int kt = 0; kt < nk; ++kt) {
        As4[sa0] = a0; As4[sa1] = a1; Bs4[sa0] = b0; Bs4[sa1] = b1;
        __syncthreads();
        if (kt + 1 < nk) {
            const size_t o = (size_t)(kt + 1) * 4;
            a0 = Ag[ia0 + o]; a1 = Ag[ia1 + o]; b0 = Bg[ib0 + o]; b1 = Bg[ib1 + o];
        }
        s16x8 af[4], bf[4];
#pragma unroll
        for (int i = 0; i < 4; ++i) af[i] = *(const s16x8*)&As[(wm + i * 16 + l16) * 40 + quad * 8];
#pragma unroll
        for (int j = 0; j < 4; ++j) bf[j] = *(const s16x8*)&Bs[(wn + j * 16 + l16) * 40 + quad * 8];
#pragma unroll
        for (int i = 0; i < 4; ++i)
#pragma unroll
            for (int j = 0; j < 4; ++j)
                acc[i][j] = __builtin_amdgcn_mfma_f32_16x16x32_bf16(af[i], bf[j], acc[i][j], 0, 0, 0);
        __syncthreads();
    }

    if (EPI == 0) {
#pragma unroll
        for (int j = 0; j < 4; ++j) {
            int col = col0 + wn + j * 16 + l16;
            float bcol = bias[col];
            float s = 0.f, s2 = 0.f;
#pragma unroll
            for (int i = 0; i < 4; ++i) {
#pragma unroll
                for (int r = 0; r < 4; ++r) {
                    int m = row0 + wm + i * 16 + quad * 4 + r;
                    float v = acc[i][j][r] + bcol;
                    C[(size_t)m * 512 + col] = v;
                    s += v; s2 += v * v;
                }
            }
            s += __shfl_xor(s, 16); s += __shfl_xor(s, 32);
            s2 += __shfl_xor(s2, 16); s2 += __shfl_xor(s2, 32);
            if (quad == 0) { atomicAdd(&bn_sum[col], s); atomicAdd(&bn_sumsq[col], s2); }
        }
    } else {
#pragma unroll
        for (int i = 0; i < 4; ++i) {
#pragma unroll
            for (int j = 0; j < 4; ++j) {
#pragma unroll
                for (int r = 0; r < 4; ++r) {
                    int m = row0 + wm + i * 16 + quad * 4 + r;
                    int n = col0 + wn + j * 16 + l16;
                    float v = acc[i][j][r];
                    v += node_w[m] * decLast[n] + decb[n];
                    v = fmaxf(v, 0.f);
                    int bb = m / 49, sp = m - bb * 49;
                    out[((size_t)bb * 512 + n) * 49 + sp] = v;   // (B,512,7,7)
                }
            }
        }
    }
}

// ---------------- BN scale/shift from sums ----------------
__global__ void k_bnstat(const float* bn_sum, const float* bn_sumsq, const float* gamma, const float* beta,
                         float* scale, float* shift) {
    int d = threadIdx.x;
    const float invN = 1.f / (float)N_NODES;
    float mu = bn_sum[d] * invN;
    float var = bn_sumsq[d] * invN - mu * mu;
    float sc = gamma[d] * rsqrtf(var + 1e-5f);
    scale[d] = sc;
    shift[d] = beta[d] - mu * sc;
}

// ---------------- fused BN-apply + relu + cast + in-neighbor aggregation; emits next GEMM A=[agg|x] ----------------
__global__ __launch_bounds__(256) void k_bnagg(const float* __restrict__ P, const float* __restrict__ ew,
                                               const float* __restrict__ asum,
                                               const float* __restrict__ scale, const float* __restrict__ shift,
                                               ushort* __restrict__ xcat) {
    int b = blockIdx.x, tid = threadIdx.x;
    __shared__ ushort xl[49 * 512];
    __shared__ float wl[49], wt[49];
    if (tid < 49) {
        int r = tid / 7, c = tid - r * 7;
        int deg = (c > 0) + (r > 0);
        float sc = deg ? (1.f / (asum[0] + 1e-8f)) / (float)deg : 0.f;
        wl[tid] = (c > 0) ? ew[b * 84 + r * 6 + (c - 1)] * sc : 0.f;
        wt[tid] = (r > 0) ? ew[b * 84 + 42 + (r - 1) * 7 + c] * sc : 0.f;
    }
    int dc = tid & 127;                 // fixed 4-col chunk per thread
    int sp0 = tid >> 7;
    float4 scl = ((const float4*)scale)[dc];
    float4 shf = ((const float4*)shift)[dc];
    for (int sp = sp0; sp < 49; sp += 2) {
        float4 v = ((const float4*)(P + ((size_t)b * 49 + sp) * 512))[dc];
        ushort4 o;
        o.x = f2bf(fmaxf(v.x * scl.x + shf.x, 0.f));
        o.y = f2bf(fmaxf(v.y * scl.y + shf.y, 0.f));
        o.z = f2bf(fmaxf(v.z * scl.z + shf.z, 0.f));
        o.w = f2bf(fmaxf(v.w * scl.w + shf.w, 0.f));
        *(ushort4*)&xl[sp * 512 + dc * 4] = o;
        ((ushort4*)(xcat + ((size_t)b * 49 + sp) * 1024 + 512))[dc] = o;
    }
    __syncthreads();
    for (int sp = sp0; sp < 49; sp += 2) {
        float a0 = 0.f, a1 = 0.f, a2 = 0.f, a3 = 0.f;
        float w1 = wl[sp], w2 = wt[sp];
        if (w1 != 0.f) {
            ushort4 u = *(const ushort4*)&xl[(sp - 1) * 512 + dc * 4];
            a0 += w1 * bf2f(u.x); a1 += w1 * bf2f(u.y); a2 += w1 * bf2f(u.z); a3 += w1 * bf2f(u.w);
        }
        if (w2 != 0.f) {
            ushort4 u = *(const ushort4*)&xl[(sp - 7) * 512 + dc * 4];
            a0 += w2 * bf2f(u.x); a1 += w2 * bf2f(u.y); a2 += w2 * bf2f(u.z); a3 += w2 * bf2f(u.w);
        }
        ushort4 o;
        o.x = f2bf(a0); o.y = f2bf(a1); o.z = f2bf(a2); o.w = f2bf(a3);
        ((ushort4*)(xcat + ((size_t)b * 49 + sp) * 1024))[dc] = o;
    }
}

// ---------------- BN apply + relu + bf16 cast (no agg; feeds dec GEMM) ----------------
__global__ void k_bnapply(const float* __restrict__ x, const float* __restrict__ scale,
                          const float* __restrict__ shift, ushort* __restrict__ xb) {
    int tid = threadIdx.x;
    size_t i = (size_t)blockIdx.x * 256 + tid;
    int dc = tid & 127;
    float4 scl = ((const float4*)scale)[dc];
    float4 shf = ((const float4*)shift)[dc];
    float4 v = ((const float4*)x)[i];
    ushort4 o;
    o.x = f2bf(fmaxf(v.x * scl.x + shf.x, 0.f));
    o.y = f2bf(fmaxf(v.y * scl.y + shf.y, 0.f));
    o.z = f2bf(fmaxf(v.z * scl.z + shf.z, 0.f));
    o.w = f2bf(fmaxf(v.w * scl.w + shf.w, 0.f));
    ((ushort4*)xb)[i] = o;
}

extern "C" void kernel_launch(void* const* d_in, const int* in_sizes, int n_in,
                              void* d_out, int out_size, void* d_ws, size_t ws_size,
                              hipStream_t stream) {
    const float* vis   = (const float*)d_in[0];
    const float* tac   = (const float*)d_in[1];
    const float* projW = (const float*)d_in[2];
    const float* projb = (const float*)d_in[3];
    const float* W1r   = (const float*)d_in[4];
    const float* b1    = (const float*)d_in[5];
    const float* W1t   = (const float*)d_in[6];
    const float* g1    = (const float*)d_in[7];
    const float* be1   = (const float*)d_in[8];
    const float* W2r   = (const float*)d_in[9];
    const float* b2    = (const float*)d_in[10];
    const float* W2t   = (const float*)d_in[11];
    const float* g2    = (const float*)d_in[12];
    const float* be2   = (const float*)d_in[13];
    const float* decW  = (const float*)d_in[14];
    const float* decb  = (const float*)d_in[15];
    float* out = (float*)d_out;

    char* p = (char*)d_ws;
    ushort* X   = (ushort*)p; p += 205520896;   // [N][2048] bf16; reused as xcat2 [N][1024] and x3b [N][512]
    float*  P   = (float*)p;  p += 102760448;   // [N][512] f32 GEMM out
    float* coords = (float*)p; p += 401408;
    float* ew     = (float*)p; p += 344064;
    float* nw     = (float*)p; p += 200704;
    ushort* Bt1   = (ushort*)p; p += 2097152;   // [512][2048]
    ushort* Bt2   = (ushort*)p; p += 1048576;   // [512][1024]
    ushort* Bt3   = (ushort*)p; p += 524288;    // [512][512]
    float* decLast = (float*)p; p += 2048;
    float* asum   = (float*)p;  p += 256;
    float* bnacc  = (float*)p;  p += 4 * 512 * 4;
    float* scsh   = (float*)p;  p += 4 * 512 * 4;
    float* bn1s = bnacc, *bn1q = bnacc + 512, *bn2s = bnacc + 1024, *bn2q = bnacc + 1536;
    float* sc1 = scsh, *sh1 = scsh + 512, *sc2 = scsh + 1024, *sh2 = scsh + 1536;

    ushort* xcat1 = X;          // [N][2048]: cols 0..1023 agg, 1024..2047 node
    ushort* xcat2 = X;          // [N][1024]: cols 0..511 agg, 512..1023 x   (aliases; sequential use)
    ushort* x3b   = X;          // [N][512]

    k_prep<<<4096, 256, 0, stream>>>(W1r, W1t, W2r, W2t, decW, Bt1, Bt2, Bt3, decLast, asum, bnacc);
    k_transpose<<<1024, 256, 0, stream>>>(vis, tac, xcat1);
    k_coords<<<12544, 256, 0, stream>>>(xcat1, projW, projb, coords);
    k_edges<<<1024, 128, 0, stream>>>(coords, ew, nw, asum);
    k_aggin<<<25088, 256, 0, stream>>>(xcat1, ew, asum);

    k_gemm<0><<<392 * 4, 256, 0, stream>>>(xcat1, Bt1, P, 2048, b1, bn1s, bn1q, nullptr, nullptr, nullptr, nullptr);
    k_bnstat<<<1, 512, 0, stream>>>(bn1s, bn1q, g1, be1, sc1, sh1);
    k_bnagg<<<1024, 256, 0, stream>>>(P, ew, asum, sc1, sh1, xcat2);

    k_gemm<0><<<392 * 4, 256, 0, stream>>>(xcat2, Bt2, P, 1024, b2, bn2s, bn2q, nullptr, nullptr, nullptr, nullptr);
    k_bnstat<<<1, 512, 0, stream>>>(bn2s, bn2q, g2, be2, sc2, sh2);
    k_bnapply<<<25088, 256, 0, stream>>>(P, sc2, sh2, x3b);

    k_gemm<1><<<392 * 4, 256, 0, stream>>>(x3b, Bt3, nullptr, 512, nullptr, nullptr, nullptr, nw, decLast, decb, out);
}

// Round 3
// 814.595 us; speedup vs baseline: 1.7023x; 1.0028x over previous
//
#include <hip/hip_runtime.h>
#include <hip/hip_bf16.h>

typedef float f32x4 __attribute__((ext_vector_type(4)));
typedef short s16x8 __attribute__((ext_vector_type(8)));

#define N_NODES 50176

static __device__ __forceinline__ ushort f2bf(float x) {
    __hip_bfloat16 h = __float2bfloat16(x);
    return *reinterpret_cast<ushort*>(&h);
}
static __device__ __forceinline__ float bf2f(ushort u) {
    __hip_bfloat16 h = *reinterpret_cast<__hip_bfloat16*>(&u);
    return __bfloat162float(h);
}

static __device__ __forceinline__ void gload_lds16(const void* g, void* l) {
    __builtin_amdgcn_global_load_lds((const __attribute__((address_space(1))) void*)g,
                                     (__attribute__((address_space(3))) void*)l, 16, 0, 0);
}

// ---------------- weight prep: Bt1[512][2048]=[W1rel;W1root]^T, Bt2[512][1024], Bt3[512][512]; zero accum ----------------
__global__ void k_prep(const float* W1r, const float* W1t, const float* W2r, const float* W2t,
                       const float* decW, ushort* Bt1, ushort* Bt2, ushort* Bt3, float* decLast,
                       float* alpha_sum, float* bn_acc) {
    int idx = blockIdx.x * 256 + threadIdx.x;
    if (idx < 512 * 2048) {                // Bt1[j][k]: k<1024 -> W1rel[k][j], else W1root[k-1024][j]
        int j = idx >> 11, k = idx & 2047;
        float v = (k < 1024) ? W1r[k * 512 + j] : W1t[(k - 1024) * 512 + j];
        Bt1[idx] = f2bf(v);
    }
    if (idx < 512 * 1024) {                // Bt2[j][k]: k<512 -> W2rel[k][j], else W2root[k-512][j]
        int j = idx >> 10, k = idx & 1023;
        float v = (k < 512) ? W2r[k * 512 + j] : W2t[(k - 512) * 512 + j];
        Bt2[idx] = f2bf(v);
    }
    if (idx < 512 * 512) {                 // Bt3[j][k] = decW(k, j)
        int j = idx >> 9, k = idx & 511;
        Bt3[idx] = f2bf(decW[k * 512 + j]);
    }
    if (idx < 512) decLast[idx] = decW[512 * 512 + idx];
    if (idx < 2048) bn_acc[idx] = 0.f;
    if (idx == 0) alpha_sum[0] = 0.f;
}

// ---------------- NCHW (vis|tac) -> xcat1 cols [1024..2048) bf16, LDS-tiled transpose ----------------
__global__ void k_transpose(const float* vis, const float* tac, ushort* xcat1) {
    int b = blockIdx.x, tid = threadIdx.x;
    __shared__ ushort tile[128 * 50];
    for (int chunk = 0; chunk < 8; ++chunk) {
        const float* src = (chunk < 4 ? vis : tac) + ((size_t)b * 512 + (chunk & 3) * 128) * 49;
        for (int p = tid; p < 128 * 49; p += 256) {
            int d = p / 49, n = p - d * 49;
            tile[d * 50 + n] = f2bf(src[p]);
        }
        __syncthreads();
        for (int p = tid; p < 49 * 64; p += 256) {
            int n = p >> 6, d2 = (p & 63) * 2;
            ushort2 o;
            o.x = tile[d2 * 50 + n];
            o.y = tile[(d2 + 1) * 50 + n];
            *(ushort2*)&xcat1[((size_t)(b * 49 + n)) * 2048 + 1024 + chunk * 128 + d2] = o;
        }
        __syncthreads();
    }
}

// ---------------- coords = node @ proj_W + proj_b ; one wave per node ----------------
__global__ void k_coords(const ushort* xcat1, const float* projW, const float* projb, float* coords) {
    __shared__ float pw[2048];
    int tid = threadIdx.x;
    for (int p = tid; p < 2048; p += 256) pw[p] = projW[p];
    __syncthreads();
    int lane = tid & 63, wave = tid >> 6;
    int n = blockIdx.x * 4 + wave;
    const ushort* row = xcat1 + (size_t)n * 2048 + 1024;
    float c0 = 0.f, c1 = 0.f;
    for (int j = 0; j < 16; ++j) {
        int d = j * 64 + lane;
        float v = bf2f(row[d]);
        c0 += v * pw[2 * d];
        c1 += v * pw[2 * d + 1];
    }
    for (int off = 32; off; off >>= 1) { c0 += __shfl_down(c0, off); c1 += __shfl_down(c1, off); }
    if (lane == 0) { coords[2 * n] = c0 + projb[0]; coords[2 * n + 1] = c1 + projb[1]; }
}

// ---------------- per-graph edges: exp(edge_attr), global alpha sum, node_w ----------------
__global__ void k_edges(const float* coords, float* ew_exp, float* node_w, float* alpha_sum) {
    int b = blockIdx.x, tid = threadIdx.x;  // blockDim = 128
    __shared__ float cx[49], cy[49], ea[84];
    __shared__ float wsum[2];
    if (tid < 49) { cx[tid] = coords[(b * 49 + tid) * 2]; cy[tid] = coords[(b * 49 + tid) * 2 + 1]; }
    __syncthreads();
    float ex = 0.f;
    if (tid < 84) {
        int s, d2;
        if (tid < 42) { int r = tid / 6, c = tid - r * 6; s = r * 7 + c; d2 = s + 1; }
        else { int t = tid - 42; int r = t / 7, c = t - r * 7; s = r * 7 + c; d2 = s + 7; }
        float dx = cx[s] - cx[d2], dy = cy[s] - cy[d2];
        float dist = sqrtf(dx * dx + dy * dy);
        float attr = 1.f / (1.f + expf(-(1.f / (dist + 1e-6f))));
        ea[tid] = attr;
        ex = expf(attr);
        ew_exp[b * 84 + tid] = ex;
    }
    for (int off = 32; off; off >>= 1) ex += __shfl_down(ex, off);
    if ((tid & 63) == 0) wsum[tid >> 6] = ex;
    __syncthreads();
    if (tid == 0) atomicAdd(alpha_sum, wsum[0] + wsum[1]);
    if (tid < 49) {
        int r = tid / 7, c = tid - r * 7;
        float s = 0.f; int cnt = 0;
        if (c > 0) { s += ea[r * 6 + c - 1]; cnt++; }
        if (c < 6) { s += ea[r * 6 + c]; cnt++; }
        if (r > 0) { s += ea[42 + (r - 1) * 7 + c]; cnt++; }
        if (r < 6) { s += ea[42 + r * 7 + c]; cnt++; }
        node_w[b * 49 + tid] = s / (float)cnt;
    }
}

// ---------------- input-side aggregation: xcat1 cols [0..1024) = weighted in-neighbor avg of node ----------------
__global__ void k_aggin(ushort* __restrict__ xcat, const float* __restrict__ ew,
                        const float* __restrict__ asum) {
    int T = blockIdx.x * 256 + threadIdx.x;    // N * 128 chunks of 8 bf16
    int n = T >> 7, ch = T & 127;
    int b = n / 49, sp = n - b * 49;
    int r = sp / 7, c = sp - r * 7;
    float acc[8];
#pragma unroll
    for (int k = 0; k < 8; ++k) acc[k] = 0.f;
    int deg = (c > 0) + (r > 0);
    if (deg) {
        float sc = (1.f / (asum[0] + 1e-8f)) / (float)deg;
        if (c > 0) {
            float wl = ew[b * 84 + r * 6 + (c - 1)] * sc;
            s16x8 lv = *(const s16x8*)(xcat + (size_t)(n - 1) * 2048 + 1024 + ch * 8);
#pragma unroll
            for (int k = 0; k < 8; ++k) acc[k] += wl * bf2f((ushort)lv[k]);
        }
        if (r > 0) {
            float wt = ew[b * 84 + 42 + (r - 1) * 7 + c] * sc;
            s16x8 tv = *(const s16x8*)(xcat + (size_t)(n - 7) * 2048 + 1024 + ch * 8);
#pragma unroll
            for (int k = 0; k < 8; ++k) acc[k] += wt * bf2f((ushort)tv[k]);
        }
    }
    s16x8 o;
#pragma unroll
    for (int k = 0; k < 8; ++k) o[k] = (short)f2bf(acc[k]);
    *(s16x8*)(xcat + (size_t)n * 2048 + ch * 8) = o;
}

// ---------------- bf16 MFMA GEMM (m97 structure): C[M][512] = A[M][K] @ Bt[512][K]^T ----------------
// 128x128 tile, BK=32, global_load_lds width=16 staging, unpadded LDS.
// LDS chunk c (1KB) = rows [c*16, c*16+16); lane l -> row c*16+(l>>2), k-16B-chunk l&3 -> LDS byte c*1024 + l*16.
template <int EPI>
__global__ __launch_bounds__(256, 2)
void k_gemm(const ushort* __restrict__ A, const ushort* __restrict__ Bt, float* __restrict__ C,
            int K,
            const float* __restrict__ bias, float* __restrict__ bn_sum, float* __restrict__ bn_sumsq,
            const float* __restrict__ node_w, const float* __restrict__ decLast,
            const float* __restrict__ decb, float* __restrict__ out) {
    __shared__ __align__(16) ushort As[128 * 32];
    __shared__ __align__(16) ushort Bs[128 * 32];
    const int rowb = blockIdx.x >> 2, colb = blockIdx.x & 3;
    const int row0 = rowb << 7, col0 = colb << 7;
    const int tid = threadIdx.x;
    const int lane = tid & 63, wave = tid >> 6;
    const int wm = (wave & 1) << 6, wn = (wave >> 1) << 6;
    const int quad = lane >> 4, l16 = lane & 15;
    const int K8 = K >> 3;

    const uint4* Ag = (const uint4*)A;
    const uint4* Bg = (const uint4*)Bt;

    // wave w stages chunks w and w+4 of both A and B
    const int c0 = wave, c1 = wave + 4;
    const int lrow = lane >> 2, lkc = lane & 3;
    const size_t iA0 = (size_t)(row0 + c0 * 16 + lrow) * K8 + lkc;
    const size_t iA1 = (size_t)(row0 + c1 * 16 + lrow) * K8 + lkc;
    const size_t iB0 = (size_t)(col0 + c0 * 16 + lrow) * K8 + lkc;
    const size_t iB1 = (size_t)(col0 + c1 * 16 + lrow) * K8 + lkc;
    ushort* lA0 = As + c0 * 512;   // wave-uniform LDS bases (512 ushorts = 1KB per chunk)
    ushort* lA1 = As + c1 * 512;
    ushort* lB0 = Bs + c0 * 512;
    ushort* lB1 = Bs + c1 * 512;

    f32x4 acc[4][4];
#pragma unroll
    for (int i = 0; i < 4; ++i)
#pragma unroll
        for (int j = 0; j < 4; ++j) acc[i][j] = (f32x4)0.f;

    const int nk = K >> 5;
    for (int kt = 0; kt < nk; ++kt) {
        const size_t o = (size_t)kt * 4;
        gload_lds16(Ag + iA0 + o, lA0);
        gload_lds16(Ag + iA1 + o, lA1);
        gload_lds16(Bg + iB0 + o, lB0);
        gload_lds16(Bg + iB1 + o, lB1);
        __syncthreads();
        s16x8 af[4], bf[4];
#pragma unroll
        for (int i = 0; i < 4; ++i) af[i] = *(const s16x8*)&As[(wm + i * 16 + l16) * 32 + quad * 8];
#pragma unroll
        for (int j = 0; j < 4; ++j) bf[j] = *(const s16x8*)&Bs[(wn + j * 16 + l16) * 32 + quad * 8];
#pragma unroll
        for (int i = 0; i < 4; ++i)
#pragma unroll
            for (int j = 0; j < 4; ++j)
                acc[i][j] = __builtin_amdgcn_mfma_f32_16x16x32_bf16(af[i], bf[j], acc[i][j], 0, 0, 0);
        __syncthreads();
    }

    if (EPI == 0) {
#pragma unroll
        for (int j = 0; j < 4; ++j) {
            int col = col0 + wn + j * 16 + l16;
            float bcol = bias[col];
            float s = 0.f, s2 = 0.f;
#pragma unroll
            for (int i = 0; i < 4; ++i) {
#pragma unroll
                for (int r = 0; r < 4; ++r) {
                    int m = row0 + wm + i * 16 + quad * 4 + r;
                    float v = acc[i][j][r] + bcol;
                    C[(size_t)m * 512 + col] = v;
                    s += v; s2 += v * v;
                }
            }
            s += __shfl_xor(s, 16); s += __shfl_xor(s, 32);
            s2 += __shfl_xor(s2, 16); s2 += __shfl_xor(s2, 32);
            if (quad == 0) { atomicAdd(&bn_sum[col], s); atomicAdd(&bn_sumsq[col], s2); }
        }
    } else {
#pragma unroll
        for (int i = 0; i < 4; ++i) {
#pragma unroll
            for (int j = 0; j < 4; ++j) {
#pragma unroll
                for (int r = 0; r < 4; ++r) {
                    int m = row0 + wm + i * 16 + quad * 4 + r;
                    int n = col0 + wn + j * 16 + l16;
                    float v = acc[i][j][r];
                    v += node_w[m] * decLast[n] + decb[n];
                    v = fmaxf(v, 0.f);
                    int bb = m / 49, sp = m - bb * 49;
                    out[((size_t)bb * 512 + n) * 49 + sp] = v;   // (B,512,7,7)
                }
            }
        }
    }
}

// ---------------- BN scale/shift from sums ----------------
__global__ void k_bnstat(const float* bn_sum, const float* bn_sumsq, const float* gamma, const float* beta,
                         float* scale, float* shift) {
    int d = threadIdx.x;
    const float invN = 1.f / (float)N_NODES;
    float mu = bn_sum[d] * invN;
    float var = bn_sumsq[d] * invN - mu * mu;
    float sc = gamma[d] * rsqrtf(var + 1e-5f);
    scale[d] = sc;
    shift[d] = beta[d] - mu * sc;
}

// ---------------- fused BN-apply + relu + cast + in-neighbor aggregation; emits next GEMM A=[agg|x] ----------------
__global__ __launch_bounds__(256) void k_bnagg(const float* __restrict__ P, const float* __restrict__ ew,
                                               const float* __restrict__ asum,
                                               const float* __restrict__ scale, const float* __restrict__ shift,
                                               ushort* __restrict__ xcat) {
    int b = blockIdx.x, tid = threadIdx.x;
    __shared__ ushort xl[49 * 512];
    __shared__ float wl[49], wt[49];
    if (tid < 49) {
        int r = tid / 7, c = tid - r * 7;
        int deg = (c > 0) + (r > 0);
        float sc = deg ? (1.f / (asum[0] + 1e-8f)) / (float)deg : 0.f;
        wl[tid] = (c > 0) ? ew[b * 84 + r * 6 + (c - 1)] * sc : 0.f;
        wt[tid] = (r > 0) ? ew[b * 84 + 42 + (r - 1) * 7 + c] * sc : 0.f;
    }
    int dc = tid & 127;                 // fixed 4-col chunk per thread
    int sp0 = tid >> 7;
    float4 scl = ((const float4*)scale)[dc];
    float4 shf = ((const float4*)shift)[dc];
    for (int sp = sp0; sp < 49; sp += 2) {
        float4 v = ((const float4*)(P + ((size_t)b * 49 + sp) * 512))[dc];
        ushort4 o;
        o.x = f2bf(fmaxf(v.x * scl.x + shf.x, 0.f));
        o.y = f2bf(fmaxf(v.y * scl.y + shf.y, 0.f));
        o.z = f2bf(fmaxf(v.z * scl.z + shf.z, 0.f));
        o.w = f2bf(fmaxf(v.w * scl.w + shf.w, 0.f));
        *(ushort4*)&xl[sp * 512 + dc * 4] = o;
        ((ushort4*)(xcat + ((size_t)b * 49 + sp) * 1024 + 512))[dc] = o;
    }
    __syncthreads();
    for (int sp = sp0; sp < 49; sp += 2) {
        float a0 = 0.f, a1 = 0.f, a2 = 0.f, a3 = 0.f;
        float w1 = wl[sp], w2 = wt[sp];
        if (w1 != 0.f) {
            ushort4 u = *(const ushort4*)&xl[(sp - 1) * 512 + dc * 4];
            a0 += w1 * bf2f(u.x); a1 += w1 * bf2f(u.y); a2 += w1 * bf2f(u.z); a3 += w1 * bf2f(u.w);
        }
        if (w2 != 0.f) {
            ushort4 u = *(const ushort4*)&xl[(sp - 7) * 512 + dc * 4];
            a0 += w2 * bf2f(u.x); a1 += w2 * bf2f(u.y); a2 += w2 * bf2f(u.z); a3 += w2 * bf2f(u.w);
        }
        ushort4 o;
        o.x = f2bf(a0); o.y = f2bf(a1); o.z = f2bf(a2); o.w = f2bf(a3);
        ((ushort4*)(xcat + ((size_t)b * 49 + sp) * 1024))[dc] = o;
    }
}

// ---------------- BN apply + relu + bf16 cast (no agg; feeds dec GEMM) ----------------
__global__ void k_bnapply(const float* __restrict__ x, const float* __restrict__ scale,
                          const float* __restrict__ shift, ushort* __restrict__ xb) {
    int tid = threadIdx.x;
    size_t i = (size_t)blockIdx.x * 256 + tid;
    int dc = tid & 127;
    float4 scl = ((const float4*)scale)[dc];
    float4 shf = ((const float4*)shift)[dc];
    float4 v = ((const float4*)x)[i];
    ushort4 o;
    o.x = f2bf(fmaxf(v.x * scl.x + shf.x, 0.f));
    o.y = f2bf(fmaxf(v.y * scl.y + shf.y, 0.f));
    o.z = f2bf(fmaxf(v.z * scl.z + shf.z, 0.f));
    o.w = f2bf(fmaxf(v.w * scl.w + shf.w, 0.f));
    ((ushort4*)xb)[i] = o;
}

extern "C" void kernel_launch(void* const* d_in, const int* in_sizes, int n_in,
                              void* d_out, int out_size, void* d_ws, size_t ws_size,
                              hipStream_t stream) {
    const float* vis   = (const float*)d_in[0];
    const float* tac   = (const float*)d_in[1];
    const float* projW = (const float*)d_in[2];
    const float* projb = (const float*)d_in[3];
    const float* W1r   = (const float*)d_in[4];
    const float* b1    = (const float*)d_in[5];
    const float* W1t   = (const float*)d_in[6];
    const float* g1    = (const float*)d_in[7];
    const float* be1   = (const float*)d_in[8];
    const float* W2r   = (const float*)d_in[9];
    const float* b2    = (const float*)d_in[10];
    const float* W2t   = (const float*)d_in[11];
    const float* g2    = (const float*)d_in[12];
    const float* be2   = (const float*)d_in[13];
    const float* decW  = (const float*)d_in[14];
    const float* decb  = (const float*)d_in[15];
    float* out = (float*)d_out;

    char* p = (char*)d_ws;
    ushort* X   = (ushort*)p; p += 205520896;   // [N][2048] bf16; reused as xcat2 [N][1024] and x3b [N][512]
    float*  P   = (float*)p;  p += 102760448;   // [N][512] f32 GEMM out
    float* coords = (float*)p; p += 401408;
    float* ew     = (float*)p; p += 344064;
    float* nw     = (float*)p; p += 200704;
    ushort* Bt1   = (ushort*)p; p += 2097152;   // [512][2048]
    ushort* Bt2   = (ushort*)p; p += 1048576;   // [512][1024]
    ushort* Bt3   = (ushort*)p; p += 524288;    // [512][512]
    float* decLast = (float*)p; p += 2048;
    float* asum   = (float*)p;  p += 256;
    float* bnacc  = (float*)p;  p += 4 * 512 * 4;
    float* scsh   = (float*)p;  p += 4 * 512 * 4;
    float* bn1s = bnacc, *bn1q = bnacc + 512, *bn2s = bnacc + 1024, *bn2q = bnacc + 1536;
    float* sc1 = scsh, *sh1 = scsh + 512, *sc2 = scsh + 1024, *sh2 = scsh + 1536;

    ushort* xcat1 = X;          // [N][2048]: cols 0..1023 agg, 1024..2047 node
    ushort* xcat2 = X;          // [N][1024]: cols 0..511 agg, 512..1023 x   (aliases; sequential use)
    ushort* x3b   = X;          // [N][512]

    k_prep<<<4096, 256, 0, stream>>>(W1r, W1t, W2r, W2t, decW, Bt1, Bt2, Bt3, decLast, asum, bnacc);
    k_transpose<<<1024, 256, 0, stream>>>(vis, tac, xcat1);
    k_coords<<<12544, 256, 0, stream>>>(xcat1, projW, projb, coords);
    k_edges<<<1024, 128, 0, stream>>>(coords, ew, nw, asum);
    k_aggin<<<25088, 256, 0, stream>>>(xcat1, ew, asum);

    k_gemm<0><<<392 * 4, 256, 0, stream>>>(xcat1, Bt1, P, 2048, b1, bn1s, bn1q, nullptr, nullptr, nullptr, nullptr);
    k_bnstat<<<1, 512, 0, stream>>>(bn1s, bn1q, g1, be1, sc1, sh1);
    k_bnagg<<<1024, 256, 0, stream>>>(P, ew, asum, sc1, sh1, xcat2);

    k_gemm<0><<<392 * 4, 256, 0, stream>>>(xcat2, Bt2, P, 1024, b2, bn2s, bn2q, nullptr, nullptr, nullptr, nullptr);
    k_bnstat<<<1, 512, 0, stream>>>(bn2s, bn2q, g2, be2, sc2, sh2);
    k_bnapply<<<25088, 256, 0, stream>>>(P, sc2, sh2, x3b);

    k_gemm<1><<<392 * 4, 256, 0, stream>>>(x3b, Bt3, nullptr, 512, nullptr, nullptr, nullptr, nw, decLast, decb, out);
}

// Round 4
// 744.148 us; speedup vs baseline: 1.8635x; 1.0947x over previous
//
#include <hip/hip_runtime.h>
#include <hip/hip_bf16.h>

typedef float f32x4 __attribute__((ext_vector_type(4)));
typedef short s16x8 __attribute__((ext_vector_type(8)));

#define N_NODES 50176

static __device__ __forceinline__ ushort f2bf(float x) {
    __hip_bfloat16 h = __float2bfloat16(x);
    return *reinterpret_cast<ushort*>(&h);
}
static __device__ __forceinline__ float bf2f(ushort u) {
    __hip_bfloat16 h = *reinterpret_cast<__hip_bfloat16*>(&u);
    return __bfloat162float(h);
}

static __device__ __forceinline__ void gload_lds16(const void* g, void* l) {
    __builtin_amdgcn_global_load_lds((const __attribute__((address_space(1))) void*)g,
                                     (__attribute__((address_space(3))) void*)l, 16, 0, 0);
}

// ---------------- weight prep: Bt1[512][2048]=[W1rel;W1root]^T, Bt2[512][1024], Bt3[512][512]; zero accum ----------------
__global__ void k_prep(const float* W1r, const float* W1t, const float* W2r, const float* W2t,
                       const float* decW, ushort* Bt1, ushort* Bt2, ushort* Bt3, float* decLast,
                       float* alpha_sum, float* bn_acc) {
    int idx = blockIdx.x * 256 + threadIdx.x;
    if (idx < 512 * 2048) {                // Bt1[j][k]: k<1024 -> W1rel[k][j], else W1root[k-1024][j]
        int j = idx >> 11, k = idx & 2047;
        float v = (k < 1024) ? W1r[k * 512 + j] : W1t[(k - 1024) * 512 + j];
        Bt1[idx] = f2bf(v);
    }
    if (idx < 512 * 1024) {                // Bt2[j][k]: k<512 -> W2rel[k][j], else W2root[k-512][j]
        int j = idx >> 10, k = idx & 1023;
        float v = (k < 512) ? W2r[k * 512 + j] : W2t[(k - 512) * 512 + j];
        Bt2[idx] = f2bf(v);
    }
    if (idx < 512 * 512) {                 // Bt3[j][k] = decW(k, j)
        int j = idx >> 9, k = idx & 511;
        Bt3[idx] = f2bf(decW[k * 512 + j]);
    }
    if (idx < 512) decLast[idx] = decW[512 * 512 + idx];
    if (idx < 2048) bn_acc[idx] = 0.f;
    if (idx == 0) alpha_sum[0] = 0.f;
}

// ---------------- fused front: NCHW->bf16 transpose + coords + edges/node_w (one block per graph) ----------------
__global__ __launch_bounds__(256) void k_front(const float* __restrict__ vis, const float* __restrict__ tac,
                                               const float* __restrict__ projW, const float* __restrict__ projb,
                                               ushort* __restrict__ xcat1, float* __restrict__ ew_exp,
                                               float* __restrict__ node_w, float* __restrict__ alpha_sum) {
    int b = blockIdx.x, tid = threadIdx.x;
    __shared__ ushort tile[128 * 50];
    __shared__ float pw[2048];
    __shared__ float cx[52], cy[52], ea[84], wsum[4];
    for (int p = tid; p < 2048; p += 256) pw[p] = projW[p];
    float a0t = 0.f, a1t = 0.f;
    const int cn = tid >> 2, dl = tid & 3;
    for (int chunk = 0; chunk < 8; ++chunk) {
        __syncthreads();                   // protect tile (and pw on first iter)
        const float* src = (chunk < 4 ? vis : tac) + ((size_t)b * 512 + (chunk & 3) * 128) * 49;
        for (int p = tid; p < 128 * 49; p += 256) {
            int d = p / 49, n = p - d * 49;
            tile[d * 50 + n] = f2bf(src[p]);
        }
        __syncthreads();
        for (int p = tid; p < 49 * 64; p += 256) {
            int n = p >> 6, d2 = (p & 63) * 2;
            ushort2 o;
            o.x = tile[d2 * 50 + n];
            o.y = tile[(d2 + 1) * 50 + n];
            *(ushort2*)&xcat1[((size_t)(b * 49 + n)) * 2048 + 1024 + chunk * 128 + d2] = o;
        }
        if (tid < 196) {
#pragma unroll 4
            for (int j = 0; j < 32; ++j) {
                int d = dl + 4 * j;
                float v = bf2f(tile[d * 50 + cn]);
                int gd = chunk * 128 + d;
                a0t += v * pw[2 * gd];
                a1t += v * pw[2 * gd + 1];
            }
        }
    }
    a0t += __shfl_down(a0t, 1); a1t += __shfl_down(a1t, 1);
    a0t += __shfl_down(a0t, 2); a1t += __shfl_down(a1t, 2);
    if (tid < 196 && dl == 0) { cx[cn] = a0t + projb[0]; cy[cn] = a1t + projb[1]; }
    __syncthreads();
    float ex = 0.f;
    if (tid < 84) {
        int s, d2;
        if (tid < 42) { int r = tid / 6, c = tid - r * 6; s = r * 7 + c; d2 = s + 1; }
        else { int t = tid - 42; int r = t / 7, c = t - r * 7; s = r * 7 + c; d2 = s + 7; }
        float dx = cx[s] - cx[d2], dy = cy[s] - cy[d2];
        float dist = sqrtf(dx * dx + dy * dy);
        float attr = 1.f / (1.f + expf(-(1.f / (dist + 1e-6f))));
        ea[tid] = attr;
        ex = expf(attr);
        ew_exp[b * 84 + tid] = ex;
    }
    for (int off = 32; off; off >>= 1) ex += __shfl_down(ex, off);
    if ((tid & 63) == 0) wsum[tid >> 6] = ex;
    __syncthreads();
    if (tid == 0) atomicAdd(alpha_sum, wsum[0] + wsum[1] + wsum[2] + wsum[3]);
    if (tid < 49) {
        int r = tid / 7, c = tid - r * 7;
        float s = 0.f; int cnt = 0;
        if (c > 0) { s += ea[r * 6 + c - 1]; cnt++; }
        if (c < 6) { s += ea[r * 6 + c]; cnt++; }
        if (r > 0) { s += ea[42 + (r - 1) * 7 + c]; cnt++; }
        if (r < 6) { s += ea[42 + r * 7 + c]; cnt++; }
        node_w[b * 49 + tid] = s / (float)cnt;
    }
}

// ---------------- input-side aggregation: xcat1 cols [0..1024) = weighted in-neighbor avg of node ----------------
__global__ void k_aggin(ushort* __restrict__ xcat, const float* __restrict__ ew,
                        const float* __restrict__ asum) {
    int T = blockIdx.x * 256 + threadIdx.x;    // N * 128 chunks of 8 bf16
    int n = T >> 7, ch = T & 127;
    int b = n / 49, sp = n - b * 49;
    int r = sp / 7, c = sp - r * 7;
    float acc[8];
#pragma unroll
    for (int k = 0; k < 8; ++k) acc[k] = 0.f;
    int deg = (c > 0) + (r > 0);
    if (deg) {
        float sc = (1.f / (asum[0] + 1e-8f)) / (float)deg;
        if (c > 0) {
            float wl = ew[b * 84 + r * 6 + (c - 1)] * sc;
            s16x8 lv = *(const s16x8*)(xcat + (size_t)(n - 1) * 2048 + 1024 + ch * 8);
#pragma unroll
            for (int k = 0; k < 8; ++k) acc[k] += wl * bf2f((ushort)lv[k]);
        }
        if (r > 0) {
            float wt = ew[b * 84 + 42 + (r - 1) * 7 + c] * sc;
            s16x8 tv = *(const s16x8*)(xcat + (size_t)(n - 7) * 2048 + 1024 + ch * 8);
#pragma unroll
            for (int k = 0; k < 8; ++k) acc[k] += wt * bf2f((ushort)tv[k]);
        }
    }
    s16x8 o;
#pragma unroll
    for (int k = 0; k < 8; ++k) o[k] = (short)f2bf(acc[k]);
    *(s16x8*)(xcat + (size_t)n * 2048 + ch * 8) = o;
}

// ---------------- bf16 MFMA GEMM: C[M][512] = A[M][K] @ Bt[512][K]^T ----------------
// 128x128 tile, BK=32, global_load_lds width=16 staging, unpadded LDS.
// XCD swizzle: bid = g*32 + colb*8 + s -> rowb = g*8+s, colb. The 4 blocks sharing an
// A-slab have equal bid%8 (same XCD under round-robin dispatch) -> A hits that XCD's L2.
template <int EPI>
__global__ __launch_bounds__(256, 2)
void k_gemm(const ushort* __restrict__ A, const ushort* __restrict__ Bt, float* __restrict__ C,
            int K,
            const float* __restrict__ bias, float* __restrict__ bn_sum, float* __restrict__ bn_sumsq,
            const float* __restrict__ node_w, const float* __restrict__ decLast,
            const float* __restrict__ decb, float* __restrict__ out) {
    __shared__ __align__(16) ushort As[128 * 32];
    __shared__ __align__(16) ushort Bs[128 * 32];
    const int bid = blockIdx.x;
    const int rowb = ((bid & 7) | ((bid >> 5) << 3));
    const int colb = (bid >> 3) & 3;
    const int row0 = rowb << 7, col0 = colb << 7;
    const int tid = threadIdx.x;
    const int lane = tid & 63, wave = tid >> 6;
    const int wm = (wave & 1) << 6, wn = (wave >> 1) << 6;
    const int quad = lane >> 4, l16 = lane & 15;
    const int K8 = K >> 3;

    const uint4* Ag = (const uint4*)A;
    const uint4* Bg = (const uint4*)Bt;

    // wave w stages chunks w and w+4 of both A and B
    const int c0 = wave, c1 = wave + 4;
    const int lrow = lane >> 2, lkc = lane & 3;
    const size_t iA0 = (size_t)(row0 + c0 * 16 + lrow) * K8 + lkc;
    const size_t iA1 = (size_t)(row0 + c1 * 16 + lrow) * K8 + lkc;
    const size_t iB0 = (size_t)(col0 + c0 * 16 + lrow) * K8 + lkc;
    const size_t iB1 = (size_t)(col0 + c1 * 16 + lrow) * K8 + lkc;
    ushort* lA0 = As + c0 * 512;   // wave-uniform LDS bases (512 ushorts = 1KB per chunk)
    ushort* lA1 = As + c1 * 512;
    ushort* lB0 = Bs + c0 * 512;
    ushort* lB1 = Bs + c1 * 512;

    f32x4 acc[4][4];
#pragma unroll
    for (int i = 0; i < 4; ++i)
#pragma unroll
        for (int j = 0; j < 4; ++j) acc[i][j] = (f32x4)0.f;

    const int nk = K >> 5;
    for (int kt = 0; kt < nk; ++kt) {
        const size_t o = (size_t)kt * 4;
        gload_lds16(Ag + iA0 + o, lA0);
        gload_lds16(Ag + iA1 + o, lA1);
        gload_lds16(Bg + iB0 + o, lB0);
        gload_lds16(Bg + iB1 + o, lB1);
        __syncthreads();
        s16x8 af[4], bf[4];
#pragma unroll
        for (int i = 0; i < 4; ++i) af[i] = *(const s16x8*)&As[(wm + i * 16 + l16) * 32 + quad * 8];
#pragma unroll
        for (int j = 0; j < 4; ++j) bf[j] = *(const s16x8*)&Bs[(wn + j * 16 + l16) * 32 + quad * 8];
#pragma unroll
        for (int i = 0; i < 4; ++i)
#pragma unroll
            for (int j = 0; j < 4; ++j)
                acc[i][j] = __builtin_amdgcn_mfma_f32_16x16x32_bf16(af[i], bf[j], acc[i][j], 0, 0, 0);
        __syncthreads();
    }

    if (EPI == 0) {
#pragma unroll
        for (int j = 0; j < 4; ++j) {
            int col = col0 + wn + j * 16 + l16;
            float bcol = bias[col];
            float s = 0.f, s2 = 0.f;
#pragma unroll
            for (int i = 0; i < 4; ++i) {
#pragma unroll
                for (int r = 0; r < 4; ++r) {
                    int m = row0 + wm + i * 16 + quad * 4 + r;
                    float v = acc[i][j][r] + bcol;
                    C[(size_t)m * 512 + col] = v;
                    s += v; s2 += v * v;
                }
            }
            s += __shfl_xor(s, 16); s += __shfl_xor(s, 32);
            s2 += __shfl_xor(s2, 16); s2 += __shfl_xor(s2, 32);
            if (quad == 0) { atomicAdd(&bn_sum[col], s); atomicAdd(&bn_sumsq[col], s2); }
        }
    } else {
#pragma unroll
        for (int i = 0; i < 4; ++i) {
#pragma unroll
            for (int j = 0; j < 4; ++j) {
#pragma unroll
                for (int r = 0; r < 4; ++r) {
                    int m = row0 + wm + i * 16 + quad * 4 + r;
                    int n = col0 + wn + j * 16 + l16;
                    float v = acc[i][j][r];
                    v += node_w[m] * decLast[n] + decb[n];
                    v = fmaxf(v, 0.f);
                    int bb = m / 49, sp = m - bb * 49;
                    out[((size_t)bb * 512 + n) * 49 + sp] = v;   // (B,512,7,7)
                }
            }
        }
    }
}

// ---------------- BN scale/shift from sums ----------------
__global__ void k_bnstat(const float* bn_sum, const float* bn_sumsq, const float* gamma, const float* beta,
                         float* scale, float* shift) {
    int d = threadIdx.x;
    const float invN = 1.f / (float)N_NODES;
    float mu = bn_sum[d] * invN;
    float var = bn_sumsq[d] * invN - mu * mu;
    float sc = gamma[d] * rsqrtf(var + 1e-5f);
    scale[d] = sc;
    shift[d] = beta[d] - mu * sc;
}

// ---------------- fused BN-apply + relu + cast + in-neighbor aggregation; emits next GEMM A=[agg|x] ----------------
__global__ __launch_bounds__(256) void k_bnagg(const float* __restrict__ P, const float* __restrict__ ew,
                                               const float* __restrict__ asum,
                                               const float* __restrict__ scale, const float* __restrict__ shift,
                                               ushort* __restrict__ xcat) {
    int b = blockIdx.x, tid = threadIdx.x;
    __shared__ ushort xl[49 * 512];
    __shared__ float wl[49], wt[49];
    if (tid < 49) {
        int r = tid / 7, c = tid - r * 7;
        int deg = (c > 0) + (r > 0);
        float sc = deg ? (1.f / (asum[0] + 1e-8f)) / (float)deg : 0.f;
        wl[tid] = (c > 0) ? ew[b * 84 + r * 6 + (c - 1)] * sc : 0.f;
        wt[tid] = (r > 0) ? ew[b * 84 + 42 + (r - 1) * 7 + c] * sc : 0.f;
    }
    int dc = tid & 127;                 // fixed 4-col chunk per thread
    int sp0 = tid >> 7;
    float4 scl = ((const float4*)scale)[dc];
    float4 shf = ((const float4*)shift)[dc];
    for (int sp = sp0; sp < 49; sp += 2) {
        float4 v = ((const float4*)(P + ((size_t)b * 49 + sp) * 512))[dc];
        ushort4 o;
        o.x = f2bf(fmaxf(v.x * scl.x + shf.x, 0.f));
        o.y = f2bf(fmaxf(v.y * scl.y + shf.y, 0.f));
        o.z = f2bf(fmaxf(v.z * scl.z + shf.z, 0.f));
        o.w = f2bf(fmaxf(v.w * scl.w + shf.w, 0.f));
        *(ushort4*)&xl[sp * 512 + dc * 4] = o;
        ((ushort4*)(xcat + ((size_t)b * 49 + sp) * 1024 + 512))[dc] = o;
    }
    __syncthreads();
    for (int sp = sp0; sp < 49; sp += 2) {
        float a0 = 0.f, a1 = 0.f, a2 = 0.f, a3 = 0.f;
        float w1 = wl[sp], w2 = wt[sp];
        if (w1 != 0.f) {
            ushort4 u = *(const ushort4*)&xl[(sp - 1) * 512 + dc * 4];
            a0 += w1 * bf2f(u.x); a1 += w1 * bf2f(u.y); a2 += w1 * bf2f(u.z); a3 += w1 * bf2f(u.w);
        }
        if (w2 != 0.f) {
            ushort4 u = *(const ushort4*)&xl[(sp - 7) * 512 + dc * 4];
            a0 += w2 * bf2f(u.x); a1 += w2 * bf2f(u.y); a2 += w2 * bf2f(u.z); a3 += w2 * bf2f(u.w);
        }
        ushort4 o;
        o.x = f2bf(a0); o.y = f2bf(a1); o.z = f2bf(a2); o.w = f2bf(a3);
        ((ushort4*)(xcat + ((size_t)b * 49 + sp) * 1024))[dc] = o;
    }
}

// ---------------- BN apply + relu + bf16 cast (no agg; feeds dec GEMM) ----------------
__global__ void k_bnapply(const float* __restrict__ x, const float* __restrict__ scale,
                          const float* __restrict__ shift, ushort* __restrict__ xb) {
    int tid = threadIdx.x;
    size_t i = (size_t)blockIdx.x * 256 + tid;
    int dc = tid & 127;
    float4 scl = ((const float4*)scale)[dc];
    float4 shf = ((const float4*)shift)[dc];
    float4 v = ((const float4*)x)[i];
    ushort4 o;
    o.x = f2bf(fmaxf(v.x * scl.x + shf.x, 0.f));
    o.y = f2bf(fmaxf(v.y * scl.y + shf.y, 0.f));
    o.z = f2bf(fmaxf(v.z * scl.z + shf.z, 0.f));
    o.w = f2bf(fmaxf(v.w * scl.w + shf.w, 0.f));
    ((ushort4*)xb)[i] = o;
}

extern "C" void kernel_launch(void* const* d_in, const int* in_sizes, int n_in,
                              void* d_out, int out_size, void* d_ws, size_t ws_size,
                              hipStream_t stream) {
    const float* vis   = (const float*)d_in[0];
    const float* tac   = (const float*)d_in[1];
    const float* projW = (const float*)d_in[2];
    const float* projb = (const float*)d_in[3];
    const float* W1r   = (const float*)d_in[4];
    const float* b1    = (const float*)d_in[5];
    const float* W1t   = (const float*)d_in[6];
    const float* g1    = (const float*)d_in[7];
    const float* be1   = (const float*)d_in[8];
    const float* W2r   = (const float*)d_in[9];
    const float* b2    = (const float*)d_in[10];
    const float* W2t   = (const float*)d_in[11];
    const float* g2    = (const float*)d_in[12];
    const float* be2   = (const float*)d_in[13];
    const float* decW  = (const float*)d_in[14];
    const float* decb  = (const float*)d_in[15];
    float* out = (float*)d_out;

    char* p = (char*)d_ws;
    ushort* X   = (ushort*)p; p += 205520896;   // [N][2048] bf16; reused as xcat2 [N][1024] and x3b [N][512]
    float*  P   = (float*)p;  p += 102760448;   // [N][512] f32 GEMM out
    float* ew     = (float*)p; p += 344064;
    float* nw     = (float*)p; p += 200704;
    ushort* Bt1   = (ushort*)p; p += 2097152;   // [512][2048]
    ushort* Bt2   = (ushort*)p; p += 1048576;   // [512][1024]
    ushort* Bt3   = (ushort*)p; p += 524288;    // [512][512]
    float* decLast = (float*)p; p += 2048;
    float* asum   = (float*)p;  p += 256;
    float* bnacc  = (float*)p;  p += 4 * 512 * 4;
    float* scsh   = (float*)p;  p += 4 * 512 * 4;
    float* bn1s = bnacc, *bn1q = bnacc + 512, *bn2s = bnacc + 1024, *bn2q = bnacc + 1536;
    float* sc1 = scsh, *sh1 = scsh + 512, *sc2 = scsh + 1024, *sh2 = scsh + 1536;

    ushort* xcat1 = X;          // [N][2048]: cols 0..1023 agg, 1024..2047 node
    ushort* xcat2 = X;          // [N][1024]: cols 0..511 agg, 512..1023 x   (aliases; sequential use)
    ushort* x3b   = X;          // [N][512]

    k_prep<<<4096, 256, 0, stream>>>(W1r, W1t, W2r, W2t, decW, Bt1, Bt2, Bt3, decLast, asum, bnacc);
    k_front<<<1024, 256, 0, stream>>>(vis, tac, projW, projb, xcat1, ew, nw, asum);
    k_aggin<<<25088, 256, 0, stream>>>(xcat1, ew, asum);

    k_gemm<0><<<392 * 4, 256, 0, stream>>>(xcat1, Bt1, P, 2048, b1, bn1s, bn1q, nullptr, nullptr, nullptr, nullptr);
    k_bnstat<<<1, 512, 0, stream>>>(bn1s, bn1q, g1, be1, sc1, sh1);
    k_bnagg<<<1024, 256, 0, stream>>>(P, ew, asum, sc1, sh1, xcat2);

    k_gemm<0><<<392 * 4, 256, 0, stream>>>(xcat2, Bt2, P, 1024, b2, bn2s, bn2q, nullptr, nullptr, nullptr, nullptr);
    k_bnstat<<<1, 512, 0, stream>>>(bn2s, bn2q, g2, be2, sc2, sh2);
    k_bnapply<<<25088, 256, 0, stream>>>(P, sc2, sh2, x3b);

    k_gemm<1><<<392 * 4, 256, 0, stream>>>(x3b, Bt3, nullptr, 512, nullptr, nullptr, nullptr, nw, decLast, decb, out);
}